// Round 1
// baseline (249.517 us; speedup 1.0000x reference)
//
#include <hip/hip_runtime.h>

#define BB 2
#define NN 2048
#define ROWS (BB*NN)   // 4096
#define RPB 8          // rows per block in big pass

__device__ __forceinline__ float fsig(float x) {
    float e = __expf(-x);
    return __builtin_amdgcn_rcpf(1.0f + e);
}

// Small per-step state kernel: computes aS_t, qC0_t, zeroes c for next pass.
// first=1: cur_S = logits_S, cur_C = logits_C (no messages yet).
__global__ void ksmall(const float* __restrict__ S, const float* __restrict__ C,
                       const float* __restrict__ w,
                       const float* __restrict__ r, float* __restrict__ c,
                       const float* __restrict__ aS_prev, float* __restrict__ aS_cur,
                       float* __restrict__ qC0, int first)
{
    int idx = blockIdx.x * blockDim.x + threadIdx.x;
    if (idx >= ROWS) return;
    float w0 = w[0], w1 = w[1];
    float S0 = S[2*idx], S1 = S[2*idx+1];
    float C0 = C[2*idx], C1 = C[2*idx+1];
    float aS, qc;
    if (first) {
        aS = fsig(S1 - S0);
        qc = fsig(C0 - C1);
    } else {
        float ap  = aS_prev[idx];
        float qcp = qC0[idx];
        float s0 = S0 + w0*qcp + w1*r[idx];
        float s1 = S1 + w1*c[idx];
        aS = fsig(s1 - s0);
        qc = fsig(C0 - C1 - w0*ap);
    }
    aS_cur[idx] = aS;
    qC0[idx]    = qc;
    c[idx]      = 0.0f;   // ready for next big pass's atomics
}

// Big pass over logits_F.
// MODE 0: first step (message term m=0), MODE 1: middle, MODE 2: final (also writes out_F).
// r[b,x] = sum_y sigmoid(dF - m) * (1-aS_cur[y]);  c[b,y] += sum_x sigmoid(dF - m) * aS_cur[x]
// m = w1 * aS_prev[x] * (1 - aS_prev[y])
template<int MODE>
__global__ __launch_bounds__(256) void kbig(
    const float4* __restrict__ F,
    const float* __restrict__ aS_cur, const float* __restrict__ aS_prev,
    const float* __restrict__ w,
    float* __restrict__ r, float* __restrict__ c,
    float4* __restrict__ outF)
{
    const int tid  = threadIdx.x;
    const int row0 = blockIdx.x * RPB;
    const int b    = row0 >> 11;           // NN = 2048 rows per batch
    const float w1 = w[1];

    // Each thread owns 4 float4 columns: j_k = tid + 256*k -> y = 2j, 2j+1
    float wq[8], bp[8];
#pragma unroll
    for (int k = 0; k < 4; k++) {
        int j = tid + 256*k;
        wq[2*k]   = 1.0f - aS_cur[b*NN + 2*j];
        wq[2*k+1] = 1.0f - aS_cur[b*NN + 2*j+1];
        if (MODE != 0) {
            bp[2*k]   = 1.0f - aS_prev[b*NN + 2*j];
            bp[2*k+1] = 1.0f - aS_prev[b*NN + 2*j+1];
        } else {
            bp[2*k] = bp[2*k+1] = 0.0f;
        }
    }

    float cacc[8] = {0,0,0,0,0,0,0,0};
    __shared__ float red[4];
    const int lane = tid & 63, wid = tid >> 6;

    for (int i = 0; i < RPB; i++) {
        const int row = row0 + i;
        const int x   = row & (NN-1);
        const float a_c = aS_cur[b*NN + x];
        float m1 = 0.0f;
        if (MODE != 0) m1 = w1 * aS_prev[b*NN + x];
        const float4* Frow = F + (size_t)row * (NN/2);
        float4* Orow = (MODE == 2) ? (outF + (size_t)row * (NN/2)) : nullptr;
        const float mw = w1 * a_c;
        float racc = 0.0f;
#pragma unroll
        for (int k = 0; k < 4; k++) {
            int j = tid + 256*k;
            float4 f = Frow[j];
            float d0 = f.y - f.x;
            float d1 = f.w - f.z;
            float s0, s1;
            if (MODE == 0) { s0 = fsig(d0); s1 = fsig(d1); }
            else           { s0 = fsig(d0 - m1*bp[2*k]); s1 = fsig(d1 - m1*bp[2*k+1]); }
            racc      += s0*wq[2*k] + s1*wq[2*k+1];
            cacc[2*k]   += s0 * a_c;
            cacc[2*k+1] += s1 * a_c;
            if (MODE == 2) {
                float4 o;
                o.x = f.x + mw*wq[2*k];
                o.y = f.y;
                o.z = f.z + mw*wq[2*k+1];
                o.w = f.w;
                Orow[j] = o;
            }
        }
        // block-reduce racc -> r[row] (block owns these rows exclusively)
#pragma unroll
        for (int off = 32; off > 0; off >>= 1) racc += __shfl_down(racc, off);
        if (lane == 0) red[wid] = racc;
        __syncthreads();
        if (tid == 0) r[row] = red[0] + red[1] + red[2] + red[3];
        __syncthreads();
    }
#pragma unroll
    for (int k = 0; k < 4; k++) {
        int j = tid + 256*k;
        atomicAdd(&c[b*NN + 2*j],   cacc[2*k]);
        atomicAdd(&c[b*NN + 2*j+1], cacc[2*k+1]);
    }
}

// Final epilogue: out_S, out_C from (qC0_4, r_4, c_4, aS_4).
__global__ void kfin(const float* __restrict__ S, const float* __restrict__ C,
                     const float* __restrict__ w,
                     const float* __restrict__ r, const float* __restrict__ c,
                     const float* __restrict__ aS4, const float* __restrict__ qC0,
                     float* __restrict__ outS, float* __restrict__ outC)
{
    int idx = blockIdx.x * blockDim.x + threadIdx.x;
    if (idx >= ROWS) return;
    float w0 = w[0], w1 = w[1];
    outS[2*idx]   = S[2*idx]   + w0*qC0[idx] + w1*r[idx];
    outS[2*idx+1] = S[2*idx+1] + w1*c[idx];
    outC[2*idx]   = C[2*idx];
    outC[2*idx+1] = C[2*idx+1] + w0*aS4[idx];
}

extern "C" void kernel_launch(void* const* d_in, const int* in_sizes, int n_in,
                              void* d_out, int out_size, void* d_ws, size_t ws_size,
                              hipStream_t stream)
{
    const float* S = (const float*)d_in[0];
    const float* C = (const float*)d_in[1];
    const float* F = (const float*)d_in[2];
    const float* w = (const float*)d_in[3];
    float* out = (float*)d_out;
    float* ws  = (float*)d_ws;

    float* aSA = ws;              // 4096
    float* aSB = ws + ROWS;       // 4096
    float* qC0 = ws + 2*ROWS;     // 4096
    float* r   = ws + 3*ROWS;     // 4096
    float* c   = ws + 4*ROWS;     // 4096  (total 80 KB of ws)

    const float4* F4 = (const float4*)F;
    float* outS = out;
    float* outC = out + 2*ROWS;               // 8192
    float4* outF = (float4*)(out + 4*ROWS);   // 16384

    dim3 gs(ROWS/256), bs(256);
    dim3 gb(ROWS/RPB), bbk(256);

    // t=0 : cur = aSA
    ksmall<<<gs, bs, 0, stream>>>(S, C, w, r, c, aSB, aSA, qC0, 1);
    kbig<0><<<gb, bbk, 0, stream>>>(F4, aSA, aSB, w, r, c, nullptr);
    // t=1 : prev = aSA, cur = aSB
    ksmall<<<gs, bs, 0, stream>>>(S, C, w, r, c, aSA, aSB, qC0, 0);
    kbig<1><<<gb, bbk, 0, stream>>>(F4, aSB, aSA, w, r, c, nullptr);
    // t=2 : prev = aSB, cur = aSA
    ksmall<<<gs, bs, 0, stream>>>(S, C, w, r, c, aSB, aSA, qC0, 0);
    kbig<1><<<gb, bbk, 0, stream>>>(F4, aSA, aSB, w, r, c, nullptr);
    // t=3 : prev = aSA, cur = aSB
    ksmall<<<gs, bs, 0, stream>>>(S, C, w, r, c, aSA, aSB, qC0, 0);
    kbig<1><<<gb, bbk, 0, stream>>>(F4, aSB, aSA, w, r, c, nullptr);
    // t=4 : prev = aSB, cur = aSA ; fused out_F write
    ksmall<<<gs, bs, 0, stream>>>(S, C, w, r, c, aSB, aSA, qC0, 0);
    kbig<2><<<gb, bbk, 0, stream>>>(F4, aSA, aSB, w, r, c, outF);
    // epilogue: out_S, out_C
    kfin<<<gs, bs, 0, stream>>>(S, C, w, r, c, aSA, qC0, outS, outC);
}

// Round 2
// 222.258 us; speedup vs baseline: 1.1226x; 1.1226x over previous
//
#include <hip/hip_runtime.h>

#define BB 2
#define NN 2048
#define ROWS (BB*NN)   // 4096
#define RPB 16         // rows per block in big pass
#define CSPLIT 4       // column splits (each block: 256 float4 cols)

__device__ __forceinline__ float fsig(float x) {
    float e = __expf(-x);
    return __builtin_amdgcn_rcpf(1.0f + e);
}

// Small per-step state kernel: computes aS_t, qC0_t, zeroes r & c for next pass.
__global__ void ksmall(const float* __restrict__ S, const float* __restrict__ C,
                       const float* __restrict__ w,
                       float* __restrict__ r, float* __restrict__ c,
                       const float* __restrict__ aS_prev, float* __restrict__ aS_cur,
                       float* __restrict__ qC0, int first)
{
    int idx = blockIdx.x * blockDim.x + threadIdx.x;
    if (idx >= ROWS) return;
    float w0 = w[0], w1 = w[1];
    float S0 = S[2*idx], S1 = S[2*idx+1];
    float C0 = C[2*idx], C1 = C[2*idx+1];
    float aS, qc;
    if (first) {
        aS = fsig(S1 - S0);
        qc = fsig(C0 - C1);
    } else {
        float ap  = aS_prev[idx];
        float qcp = qC0[idx];
        float s0 = S0 + w0*qcp + w1*r[idx];
        float s1 = S1 + w1*c[idx];
        aS = fsig(s1 - s0);
        qc = fsig(C0 - C1 - w0*ap);
    }
    aS_cur[idx] = aS;
    qC0[idx]    = qc;
    r[idx]      = 0.0f;   // ready for next big pass's atomics
    c[idx]      = 0.0f;
}

// Big pass over logits_F. No barriers; wave-level r reduction via shfl+atomic.
// MODE 0: first step (m=0), MODE 1: middle, MODE 2: final (also writes out_F).
// r[b,x] = sum_y sig(dF - m)*(1-aS_cur[y]);  c[b,y] += sum_x sig(dF - m)*aS_cur[x]
// m = w1 * aS_prev[x] * (1 - aS_prev[y])
template<int MODE>
__global__ __launch_bounds__(256) void kbig(
    const float4* __restrict__ F,
    const float* __restrict__ aS_cur, const float* __restrict__ aS_prev,
    const float* __restrict__ w,
    float* __restrict__ r, float* __restrict__ c,
    float4* __restrict__ outF)
{
    const int tid  = threadIdx.x;
    const int j    = blockIdx.x * 256 + tid;     // float4 column in [0, NN/2)
    const int row0 = blockIdx.y * RPB;
    const int b    = row0 >> 11;                 // 2048 rows per batch
    const int lane = tid & 63;
    const float w1 = w[1];

    const float wq0 = 1.0f - aS_cur[b*NN + 2*j];
    const float wq1 = 1.0f - aS_cur[b*NN + 2*j + 1];
    float bp0 = 0.0f, bp1 = 0.0f;
    if (MODE != 0) {
        bp0 = 1.0f - aS_prev[b*NN + 2*j];
        bp1 = 1.0f - aS_prev[b*NN + 2*j + 1];
    }

    float c0 = 0.0f, c1 = 0.0f;

#pragma unroll 2
    for (int i = 0; i < RPB; i++) {
        const int row = row0 + i;
        const int x   = row & (NN - 1);
        const float a_c = aS_cur[b*NN + x];
        float m1 = 0.0f;
        if (MODE != 0) m1 = w1 * aS_prev[b*NN + x];

        const float4 f = F[(size_t)row * (NN/2) + j];
        const float d0 = f.y - f.x;
        const float d1 = f.w - f.z;
        float s0, s1;
        if (MODE == 0) { s0 = fsig(d0); s1 = fsig(d1); }
        else           { s0 = fsig(d0 - m1*bp0); s1 = fsig(d1 - m1*bp1); }

        c0 += s0 * a_c;
        c1 += s1 * a_c;

        if (MODE == 2) {
            const float mw = w1 * a_c;
            float4 o;
            o.x = f.x + mw*wq0;
            o.y = f.y;
            o.z = f.z + mw*wq1;
            o.w = f.w;
            outF[(size_t)row * (NN/2) + j] = o;
        }

        // r partial for this row: wave reduce, one atomic per wave (rows are
        // exclusive to this (block.y); only CSPLIT blocks share a row).
        float ra = s0*wq0 + s1*wq1;
#pragma unroll
        for (int off = 32; off > 0; off >>= 1) ra += __shfl_down(ra, off);
        if (lane == 0) atomicAdd(&r[row], ra);
    }

    atomicAdd(&c[b*NN + 2*j],     c0);
    atomicAdd(&c[b*NN + 2*j + 1], c1);
}

// Final epilogue: out_S, out_C from (qC0_4, r_4, c_4, aS_4).
__global__ void kfin(const float* __restrict__ S, const float* __restrict__ C,
                     const float* __restrict__ w,
                     const float* __restrict__ r, const float* __restrict__ c,
                     const float* __restrict__ aS4, const float* __restrict__ qC0,
                     float* __restrict__ outS, float* __restrict__ outC)
{
    int idx = blockIdx.x * blockDim.x + threadIdx.x;
    if (idx >= ROWS) return;
    float w0 = w[0], w1 = w[1];
    outS[2*idx]   = S[2*idx]   + w0*qC0[idx] + w1*r[idx];
    outS[2*idx+1] = S[2*idx+1] + w1*c[idx];
    outC[2*idx]   = C[2*idx];
    outC[2*idx+1] = C[2*idx+1] + w0*aS4[idx];
}

extern "C" void kernel_launch(void* const* d_in, const int* in_sizes, int n_in,
                              void* d_out, int out_size, void* d_ws, size_t ws_size,
                              hipStream_t stream)
{
    const float* S = (const float*)d_in[0];
    const float* C = (const float*)d_in[1];
    const float* F = (const float*)d_in[2];
    const float* w = (const float*)d_in[3];
    float* out = (float*)d_out;
    float* ws  = (float*)d_ws;

    float* aSA = ws;              // 4096
    float* aSB = ws + ROWS;       // 4096
    float* qC0 = ws + 2*ROWS;     // 4096
    float* r   = ws + 3*ROWS;     // 4096
    float* c   = ws + 4*ROWS;     // 4096  (total 80 KB of ws)

    const float4* F4 = (const float4*)F;
    float* outS = out;
    float* outC = out + 2*ROWS;               // 8192
    float4* outF = (float4*)(out + 4*ROWS);   // 16384 float4s per... rest

    dim3 gs(ROWS/256), bs(256);
    dim3 gb(CSPLIT, ROWS/RPB), bbk(256);

    // t=0 : cur = aSA
    ksmall<<<gs, bs, 0, stream>>>(S, C, w, r, c, aSB, aSA, qC0, 1);
    kbig<0><<<gb, bbk, 0, stream>>>(F4, aSA, aSB, w, r, c, nullptr);
    // t=1 : prev = aSA, cur = aSB
    ksmall<<<gs, bs, 0, stream>>>(S, C, w, r, c, aSA, aSB, qC0, 0);
    kbig<1><<<gb, bbk, 0, stream>>>(F4, aSB, aSA, w, r, c, nullptr);
    // t=2 : prev = aSB, cur = aSA
    ksmall<<<gs, bs, 0, stream>>>(S, C, w, r, c, aSB, aSA, qC0, 0);
    kbig<1><<<gb, bbk, 0, stream>>>(F4, aSA, aSB, w, r, c, nullptr);
    // t=3 : prev = aSA, cur = aSB
    ksmall<<<gs, bs, 0, stream>>>(S, C, w, r, c, aSA, aSB, qC0, 0);
    kbig<1><<<gb, bbk, 0, stream>>>(F4, aSB, aSA, w, r, c, nullptr);
    // t=4 : prev = aSB, cur = aSA ; fused out_F write
    ksmall<<<gs, bs, 0, stream>>>(S, C, w, r, c, aSB, aSA, qC0, 0);
    kbig<2><<<gb, bbk, 0, stream>>>(F4, aSA, aSB, w, r, c, outF);
    // epilogue: out_S, out_C
    kfin<<<gs, bs, 0, stream>>>(S, C, w, r, c, aSA, qC0, outS, outC);
}